// Round 18
// baseline (338.812 us; speedup 1.0000x reference)
//
#include <hip/hip_runtime.h>
#include <hip/hip_bf16.h>
#include <stdint.h>
#include <stddef.h>

// Problem constants
#define D_DIM 2048
#define H_HEADS 16
#define KV_HEADS 4
#define HEAD_DIM 128
#define SEQ_L 2048
#define BATCH 2
#define NTOK 4096      // BATCH*SEQ_L
#define NQK 2560       // D + KV_HEADS*HEAD_DIM (Q+K rows; V handled via transposed path)
#define NQKV 3072      // Q+K+V rows in the merged projection

typedef __attribute__((ext_vector_type(4))) float f32x4;
typedef __attribute__((ext_vector_type(16))) float f32x16;
typedef __attribute__((ext_vector_type(8))) short bf16x8;

__device__ __forceinline__ unsigned short f2bf(float f) {
  __hip_bfloat16 h = __float2bfloat16(f);            // RTNE
  return *reinterpret_cast<unsigned short*>(&h);
}
__device__ __forceinline__ unsigned pack2(float lo, float hi) {
  return (unsigned)f2bf(lo) | ((unsigned)f2bf(hi) << 16);
}
__device__ __forceinline__ float bf2f(unsigned int s) {
  return __uint_as_float(s << 16);
}
__device__ __forceinline__ void plane32swap(unsigned& a, unsigned& b) {
  asm volatile("v_permlane32_swap_b32 %0, %1" : "+v"(a), "+v"(b));
}
__device__ __forceinline__ float exp2g(float x) {
  return __builtin_amdgcn_exp2f(x);                  // raw v_exp_f32 (2^x)
}

__device__ __forceinline__ void async_copy16(const void* g, void* l) {
  __builtin_amdgcn_global_load_lds(
      (__attribute__((address_space(1))) void*)(g),
      (__attribute__((address_space(3))) void*)(l),
      16, 0, 0);
}

// ---------------- fused fp32->bf16 casts + RoPE table (segment per blockIdx.y) ----------------
__device__ __forceinline__ void cast_seg(const float* __restrict__ src,
                                         unsigned short* __restrict__ dst,
                                         int n4, int gid, int stride) {
  for (int i = gid; i < n4; i += stride) {
    float4 v = *reinterpret_cast<const float4*>(src + (size_t)i * 4);
    uint2 o;
    o.x = pack2(v.x, v.y);
    o.y = pack2(v.z, v.w);
    *reinterpret_cast<uint2*>(dst + (size_t)i * 4) = o;
  }
}

__global__ __launch_bounds__(256) void fused_cast_kernel(
    const float* __restrict__ s0, const float* __restrict__ s1,
    const float* __restrict__ s2, const float* __restrict__ s3,
    const float* __restrict__ s4,
    unsigned short* __restrict__ d0, unsigned short* __restrict__ d1,
    unsigned short* __restrict__ d2, unsigned short* __restrict__ d3,
    unsigned short* __restrict__ d4,
    float* __restrict__ cosT, float* __restrict__ sinT) {
  int gid = blockIdx.x * blockDim.x + threadIdx.x;
  const int stride = 512 * 256;
  const size_t xh = (size_t)NTOK * D_DIM / 2;       // half of x, elements
  switch (blockIdx.y) {
    case 0: cast_seg(s0, d0, (NTOK * D_DIM) / 8, gid, stride); break;      // x lo half
    case 1: cast_seg(s0 + xh, d0 + xh, (NTOK * D_DIM) / 8, gid, stride); break;  // x hi half
    case 2: cast_seg(s1, d1, (D_DIM * D_DIM) / 4, gid, stride); break;     // wq
    case 3: cast_seg(s4, d4, (D_DIM * D_DIM) / 4, gid, stride); break;     // wo
    case 4:
      cast_seg(s2, d2, (512 * D_DIM) / 4, gid, stride);                    // wk
      cast_seg(s3, d3, (512 * D_DIM) / 4, gid, stride);                    // wv
      break;
    default: {                                                             // RoPE table
      int p = gid & 63;
      float l = (float)(gid >> 6);
      float inv = powf(10000.0f, -(float)p / 64.0f);
      float ang = l * inv;
      cosT[gid] = cosf(ang);
      sinT[gid] = sinf(ang);
    }
  }
}

// ---------------- GEMM: C[M,N] = A[M,K] * B[N,K]^T  (bf16 in, OutT out) ----------------
__device__ __forceinline__ void store_out(unsigned short* p, float v) { *p = f2bf(v); }
__device__ __forceinline__ void store_out(float* p, float v) { *p = v; }

template <typename OutT, bool VSPLIT>
__global__ __launch_bounds__(256) void gemm_bt_kernel(const unsigned short* __restrict__ A,
                                                      const unsigned short* __restrict__ B,
                                                      OutT* __restrict__ C,
                                                      unsigned short* __restrict__ vt,
                                                      int M, int N, int K) {
  __shared__ unsigned short Alds[128 * 32];
  __shared__ unsigned short Blds[128 * 32];
  const int tid = threadIdx.x;
  const int wave = tid >> 6;
  const int lane = tid & 63;
  const int l15 = lane & 15;
  const int l4 = lane >> 4;

  // XCD-aware bijective swizzle (T1)
  const int nwg = gridDim.x * gridDim.y;
  const int orig = blockIdx.y * gridDim.x + blockIdx.x;
  const int cpx = nwg >> 3;
  const int swz = (orig & 7) * cpx + (orig >> 3);
  const int m0 = (swz % gridDim.x) * 128;
  const int n0 = (swz / gridDim.x) * 128;

  const int wm = (wave >> 1) * 64;
  const int wn = (wave & 1) * 64;

  f32x4 acc[4][4] = {};

  const int soff0 = wave * 1024 + lane * 16;  // bytes within 8KB tile

  for (int kt = 0; kt < K; kt += 32) {
#pragma unroll
    for (int inst = 0; inst < 2; ++inst) {
      int off = soff0 + inst * 4096;
      int row = off >> 6;    // 64 bytes (32 bf16) per LDS row
      int colb = off & 63;
      const char* ga = (const char*)(A + (size_t)(m0 + row) * K + kt) + colb;
      async_copy16(ga, (char*)Alds + off);
      const char* gb = (const char*)(B + (size_t)(n0 + row) * K + kt) + colb;
      async_copy16(gb, (char*)Blds + off);
    }
    __syncthreads();
    bf16x8 af[4], bfr[4];
#pragma unroll
    for (int i = 0; i < 4; ++i)
      af[i] = *reinterpret_cast<const bf16x8*>(Alds + (wm + i * 16 + l15) * 32 + l4 * 8);
#pragma unroll
    for (int j = 0; j < 4; ++j)
      bfr[j] = *reinterpret_cast<const bf16x8*>(Blds + (wn + j * 16 + l15) * 32 + l4 * 8);
#pragma unroll
    for (int i = 0; i < 4; ++i)
#pragma unroll
      for (int j = 0; j < 4; ++j)
        acc[i][j] = __builtin_amdgcn_mfma_f32_16x16x32_bf16(af[i], bfr[j], acc[i][j], 0, 0, 0);
    __syncthreads();
  }

  if (VSPLIT && n0 >= NQK) {
    // V block: write transposed into vt[dv][token]
#pragma unroll
    for (int i = 0; i < 4; ++i)
#pragma unroll
      for (int j = 0; j < 4; ++j) {
        int vrow = n0 + wn + j * 16 + l15 - NQK;
        int tok0 = m0 + wm + i * 16 + l4 * 4;
        ushort4 pk;
        pk.x = f2bf(acc[i][j][0]);
        pk.y = f2bf(acc[i][j][1]);
        pk.z = f2bf(acc[i][j][2]);
        pk.w = f2bf(acc[i][j][3]);
        *reinterpret_cast<ushort4*>(vt + (size_t)vrow * NTOK + tok0) = pk;
      }
    return;
  }

  const int cstride = VSPLIT ? NQK : N;
#pragma unroll
  for (int i = 0; i < 4; ++i)
#pragma unroll
    for (int j = 0; j < 4; ++j) {
      int col = n0 + wn + j * 16 + l15;
#pragma unroll
      for (int r = 0; r < 4; ++r) {
        int row = m0 + wm + i * 16 + l4 * 4 + r;
        store_out(C + (size_t)row * cstride + col, acc[i][j][r]);
      }
    }
}

// ---------------- RMSNorm + RoPE (in-place, 2 rows per wave, 8B/lane) ----------------
// Q rows get 1/sqrt(128)*log2(e) folded in (softmax runs in exp2 domain).
__global__ __launch_bounds__(256) void norm_rope_kernel(unsigned short* __restrict__ qk,
                                                        const float* __restrict__ qw,
                                                        const float* __restrict__ kw,
                                                        const float* __restrict__ cosT,
                                                        const float* __restrict__ sinT) {
  int gw = (blockIdx.x * blockDim.x + threadIdx.x) >> 6;  // wave id
  int lane = threadIdx.x & 63;
  int half = lane >> 5;         // which of the wave's 2 rows
  int L = lane & 31;            // dim-quad index: dims 4L..4L+3
  int rho = gw * 2 + half;      // row id
  unsigned short* rowp;
  const float* w;
  int m;
  float sc;
  if (rho < NTOK * H_HEADS) {
    m = rho >> 4;
    rowp = qk + (size_t)m * NQK + (rho & 15) * HEAD_DIM;
    w = qw;
    sc = 0.12751743448f;         // (1/sqrt(128)) * log2(e)  -> exp2-domain softmax
  } else {
    int r2 = rho - NTOK * H_HEADS;
    m = r2 >> 2;
    rowp = qk + (size_t)m * NQK + D_DIM + (r2 & 3) * HEAD_DIM;
    w = kw;
    sc = 1.0f;
  }
  int l = m & (SEQ_L - 1);
  uint2 pr = *reinterpret_cast<const uint2*>(rowp + L * 4);
  float e0 = bf2f(pr.x & 0xffffu), o0 = bf2f(pr.x >> 16);
  float e1 = bf2f(pr.y & 0xffffu), o1 = bf2f(pr.y >> 16);
  float ss = e0 * e0 + o0 * o0 + e1 * e1 + o1 * o1;
#pragma unroll
  for (int off = 1; off < 32; off <<= 1) ss += __shfl_xor(ss, off);  // per 32-lane half
  float rsn = rsqrtf(ss * (1.0f / 128.0f) + 1e-6f) * sc;
  float4 wv4 = *reinterpret_cast<const float4*>(w + L * 4);
  float2 c2 = *reinterpret_cast<const float2*>(cosT + l * 64 + L * 2);
  float2 s2 = *reinterpret_cast<const float2*>(sinT + l * 64 + L * 2);
  float xe0 = e0 * rsn * wv4.x, xo0 = o0 * rsn * wv4.y;
  float xe1 = e1 * rsn * wv4.z, xo1 = o1 * rsn * wv4.w;
  uint2 outp;
  outp.x = pack2(xe0 * c2.x - xo0 * s2.x, xe0 * s2.x + xo0 * c2.x);
  outp.y = pack2(xe1 * c2.y - xo1 * s2.y, xe1 * s2.y + xo1 * c2.y);
  *reinterpret_cast<uint2*>(rowp + L * 4) = outp;
}

// ---------------- Flash attention v12 (champion + exp2-domain softmax) ----------------
// K single-buffered, V double-buffered, all staging via global_load_lds.
// LDS 48.5KB -> 3 blocks/CU, 12 waves/CU. launch_bounds(256,3): VGPR ~84, no spill.
__global__ __launch_bounds__(256, 3) void attn_kernel(const unsigned short* __restrict__ qk,
                                                      const unsigned short* __restrict__ vt,
                                                      unsigned short* __restrict__ obuf,
                                                      unsigned short* __restrict__ p2,
                                                      float* __restrict__ m1G, float* __restrict__ l1G,
                                                      float* __restrict__ m2G, float* __restrict__ l2G) {
  __shared__ unsigned short Kl[64 * 128];      // [key][d], XOR-swizzled rows (256B), single
  __shared__ unsigned short Vl[2][128 * 64];   // [d][key], XOR-swizzled rows (128B), dbuf
  __shared__ float invl[128];

  const int tid = threadIdx.x;
  const int w = tid >> 6, lane = tid & 63;
  const int l31 = lane & 31, hi = lane >> 5;

  const int jx = blockIdx.x;                   // 0..23, roughly longest-first
  int qt, seg, kv_begin, kv_end;
  bool split;
  if (jx < 16) {
    split = true;
    qt = 15 - (jx >> 1);
    seg = jx & 1;
    int nt = qt + 1;
    kv_begin = seg * nt;
    kv_end = kv_begin + nt;
  } else {
    split = false;
    seg = 0;
    qt = 23 - jx;
    kv_begin = 0;
    kv_end = 2 * qt + 2;
  }
  const int q0 = qt * 128;

  const int bh = blockIdx.y;
  const int b = bh >> 4, h = bh & 15, kvh = h >> 2;

  const unsigned short* Qg = qk + (size_t)(b * SEQ_L + q0 + w * 32 + l31) * NQK + h * HEAD_DIM;
  const unsigned short* Kg = qk + (size_t)(b * SEQ_L) * NQK + D_DIM + kvh * HEAD_DIM;
  const unsigned short* Vg = vt + (size_t)(kvh * HEAD_DIM) * NTOK + b * SEQ_L;

  // Q fragments in registers: qf[kk] = Q[q=l31][kk*16 + hi*8 .. +7]
  bf16x8 qf[8];
#pragma unroll
  for (int kk = 0; kk < 8; ++kk)
    qf[kk] = *reinterpret_cast<const bf16x8*>(Qg + kk * 16 + hi * 8);

  f32x16 accO[4] = {};
  float m_run = -1e30f, l_run = 0.0f;

  const int qmin_w = q0 + w * 32;
  const int qmax_w = qmin_w + 31;
  const int qg = qmin_w + l31;

  auto stageK = [&](int kt) {
#pragma unroll
    for (int i = 0; i < 4; ++i) {
      int o = (i * 256 + tid) * 16;   // byte offset within 16KB K tile
      int row = o >> 8;
      int scb = (o & 255) ^ ((row & 7) << 4);
      const char* src = (const char*)(Kg + (size_t)(kt * 64 + row) * NQK) + scb;
      async_copy16(src, (char*)Kl + o);
    }
  };
  auto stageV = [&](int vb, int kt) {
#pragma unroll
    for (int i = 0; i < 4; ++i) {
      int o = (i * 256 + tid) * 16;   // byte offset within 16KB V^T tile
      int d = o >> 7;
      int skb = (o & 127) ^ ((d & 7) << 4);
      const char* src = (const char*)(Vg + (size_t)d * NTOK + kt * 64) + skb;
      async_copy16(src, (char*)(&Vl[vb][0]) + o);
    }
  };

  stageK(kv_begin);
  stageV(0, kv_begin);
  asm volatile("s_waitcnt vmcnt(0)" ::: "memory");
  __syncthreads();

  int vb = 0;
  for (int kt = kv_begin; kt < kv_end; ++kt) {
    const bool active = (kt * 64 <= qmax_w);
    bf16x8 pa[2][2];

    if (active) {
      // ---- QK^T: S^T[key][q], two 32-key sub-tiles ----
      f32x16 st[2] = {};
      __builtin_amdgcn_s_setprio(1);
#pragma unroll
      for (int stile = 0; stile < 2; ++stile) {
#pragma unroll
        for (int kk = 0; kk < 8; ++kk) {
          int row = stile * 32 + l31;
          int off = (row << 8) + (((kk << 5) + (hi << 4)) ^ ((l31 & 7) << 4));
          bf16x8 kf = *reinterpret_cast<const bf16x8*>((const char*)Kl + off);
          st[stile] = __builtin_amdgcn_mfma_f32_32x32x16_bf16(kf, qf[kk], st[stile], 0, 0, 0);
        }
      }
      __builtin_amdgcn_s_setprio(0);

      // ---- mask + per-lane online softmax (exp2 domain; scale pre-folded into Q) ----
      const bool need_mask = (kt * 64 + 63 > qmin_w);
      float tmax = -1e30f;
#pragma unroll
      for (int stile = 0; stile < 2; ++stile)
#pragma unroll
        for (int r = 0; r < 16; ++r) {
          float s = st[stile][r];
          if (need_mask) {
            int key = kt * 64 + stile * 32 + (r & 3) + ((r >> 2) << 3) + (hi << 2);
            if (key > qg) s = -1e30f;
          }
          st[stile][r] = s;
          tmax = fmaxf(tmax, s);
        }
      tmax = fmaxf(tmax, __shfl_xor(tmax, 32));

      // ---- defer-max (T13): P bounded by 2^8 when deferred ----
      if (!__all(tmax - m_run <= 8.0f)) {
        float mnew = fmaxf(m_run, tmax);
        float corr = exp2g(m_run - mnew);
        m_run = mnew;
        l_run *= corr;
        float corrq[16];
#pragma unroll
        for (int r = 0; r < 16; ++r) {
          int qi = (r & 3) + ((r >> 2) << 3) + (hi << 2);
          corrq[r] = __shfl(corr, qi);
        }
#pragma unroll
        for (int dt = 0; dt < 4; ++dt)
#pragma unroll
          for (int r = 0; r < 16; ++r) accO[dt][r] *= corrq[r];
      }

      float rsum = 0.0f;
#pragma unroll
      for (int stile = 0; stile < 2; ++stile)
#pragma unroll
        for (int r = 0; r < 16; ++r) {
          float pe = exp2g(st[stile][r] - m_run);
          st[stile][r] = pe;
          rsum += pe;
        }
      rsum += __shfl_xor(rsum, 32);
      l_run += rsum;

      // ---- P -> bf16 A-fragments via permlane32_swap (T12) ----
#pragma unroll
      for (int stile = 0; stile < 2; ++stile)
#pragma unroll
        for (int kc = 0; kc < 2; ++kc) {
          int rb = kc * 8;
          unsigned a  = pack2(st[stile][rb + 0], st[stile][rb + 1]);
          unsigned bw = pack2(st[stile][rb + 4], st[stile][rb + 5]);
          unsigned c  = pack2(st[stile][rb + 2], st[stile][rb + 3]);
          unsigned d  = pack2(st[stile][rb + 6], st[stile][rb + 7]);
          plane32swap(a, bw);
          plane32swap(c, d);
          union { bf16x8 v; unsigned u[4]; } uu;
          uu.u[0] = a; uu.u[1] = c; uu.u[2] = bw; uu.u[3] = d;
          pa[stile][kc] = uu.v;
        }
    }

    // V(kt+1) -> other V buffer (no reader conflict; completion enforced at loop end)
    if (kt + 1 < kv_end) stageV(vb ^ 1, kt + 1);

    __syncthreads();                // all waves done reading Kl(kt)

    if (kt + 1 < kv_end) stageK(kt + 1);   // overwrite Kl; latency hides under PV

    if (active) {
      // ---- PV: O[q][d] += P * V ----
      __builtin_amdgcn_s_setprio(1);
#pragma unroll
      for (int dt = 0; dt < 4; ++dt) {
        int drow = dt * 32 + l31;
#pragma unroll
        for (int stile = 0; stile < 2; ++stile)
#pragma unroll
          for (int kc = 0; kc < 2; ++kc) {
            int off = (drow << 7) + (((stile << 6) + (kc << 5) + (hi << 4)) ^ ((l31 & 7) << 4));
            bf16x8 vf = *reinterpret_cast<const bf16x8*>((const char*)(&Vl[vb][0]) + off);
            accO[dt] = __builtin_amdgcn_mfma_f32_32x32x16_bf16(pa[stile][kc], vf, accO[dt], 0, 0, 0);
          }
      }
      __builtin_amdgcn_s_setprio(0);
    }

    asm volatile("s_waitcnt vmcnt(0)" ::: "memory");
    __syncthreads();                // K(kt+1), V(kt+1) resident
    vb ^= 1;
  }

  if (!split) {
    // ---- direct epilogue: O /= l ----
    if (hi == 0) invl[w * 32 + l31] = 1.0f / l_run;
    __syncthreads();
#pragma unroll
    for (int dt = 0; dt < 4; ++dt)
#pragma unroll
      for (int r = 0; r < 16; ++r) {
        int qrow = (r & 3) + ((r >> 2) << 3) + (hi << 2);
        float val = accO[dt][r] * invl[w * 32 + qrow];
        int tok = b * SEQ_L + q0 + w * 32 + qrow;
        obuf[(size_t)tok * D_DIM + h * HEAD_DIM + dt * 32 + l31] = f2bf(val);
      }
  } else {
    // ---- partial epilogue: unnormalized O + (m,l) per row (m in exp2 domain) ----
    const int rowbase = bh * 1024 + (qt - 8) * 128;  // split rows: qt in [8,16)
    if (hi == 0) {
      int rr = rowbase + w * 32 + l31;
      if (seg == 0) { m1G[rr] = m_run; l1G[rr] = l_run; }
      else          { m2G[rr] = m_run; l2G[rr] = l_run; }
    }
#pragma unroll
    for (int dt = 0; dt < 4; ++dt)
#pragma unroll
      for (int r = 0; r < 16; ++r) {
        int qrow = (r & 3) + ((r >> 2) << 3) + (hi << 2);
        float val = accO[dt][r];
        if (seg == 0) {
          int tok = b * SEQ_L + q0 + w * 32 + qrow;
          obuf[(size_t)tok * D_DIM + h * HEAD_DIM + dt * 32 + l31] = f2bf(val);
        } else {
          size_t prow = (size_t)(rowbase + w * 32 + qrow);
          p2[prow * HEAD_DIM + dt * 32 + l31] = f2bf(val);
        }
      }
  }
}

// ---------------- combine kernel: merge split-KV partials (exp2 domain) ----------------
__global__ __launch_bounds__(256) void combine_kernel(unsigned short* __restrict__ obuf,
                                                      const unsigned short* __restrict__ p2,
                                                      const float* __restrict__ m1G, const float* __restrict__ l1G,
                                                      const float* __restrict__ m2G, const float* __restrict__ l2G) {
  int gid = blockIdx.x * blockDim.x + threadIdx.x;   // 32768 rows x 16 chunks
  int row = gid >> 4;
  int dc = (gid & 15) * 8;
  int bh = row >> 10;
  int rem = row & 1023;
  int qt = 8 + (rem >> 7);
  int rr = rem & 127;
  int b = bh >> 4, h = bh & 15;
  size_t tok = (size_t)(b * SEQ_L + qt * 128 + rr);

  float m1 = m1G[row], l1 = l1G[row], m2 = m2G[row], l2 = l2G[row];
  float mm = fmaxf(m1, m2);
  float w1 = __builtin_amdgcn_exp2f(m1 - mm), w2 = __builtin_amdgcn_exp2f(m2 - mm);
  float inv = 1.0f / (w1 * l1 + w2 * l2);

  unsigned short* op = obuf + tok * D_DIM + h * HEAD_DIM + dc;
  const unsigned short* pp = p2 + (size_t)row * HEAD_DIM + dc;
  ushort4 a0 = *reinterpret_cast<const ushort4*>(op);
  ushort4 a1 = *reinterpret_cast<const ushort4*>(op + 4);
  ushort4 b0 = *reinterpret_cast<const ushort4*>(pp);
  ushort4 b1 = *reinterpret_cast<const ushort4*>(pp + 4);
  ushort4 o0, o1;
  o0.x = f2bf((w1 * bf2f(a0.x) + w2 * bf2f(b0.x)) * inv);
  o0.y = f2bf((w1 * bf2f(a0.y) + w2 * bf2f(b0.y)) * inv);
  o0.z = f2bf((w1 * bf2f(a0.z) + w2 * bf2f(b0.z)) * inv);
  o0.w = f2bf((w1 * bf2f(a0.w) + w2 * bf2f(b0.w)) * inv);
  o1.x = f2bf((w1 * bf2f(a1.x) + w2 * bf2f(b1.x)) * inv);
  o1.y = f2bf((w1 * bf2f(a1.y) + w2 * bf2f(b1.y)) * inv);
  o1.z = f2bf((w1 * bf2f(a1.z) + w2 * bf2f(b1.z)) * inv);
  o1.w = f2bf((w1 * bf2f(a1.w) + w2 * bf2f(b1.w)) * inv);
  *reinterpret_cast<ushort4*>(op) = o0;
  *reinterpret_cast<ushort4*>(op + 4) = o1;
}

// ---------------- launcher ----------------
extern "C" void kernel_launch(void* const* d_in, const int* in_sizes, int n_in,
                              void* d_out, int out_size, void* d_ws, size_t ws_size,
                              hipStream_t stream) {
  const float* x   = (const float*)d_in[0];
  const float* wq  = (const float*)d_in[1];
  const float* wk  = (const float*)d_in[2];
  const float* wv  = (const float*)d_in[3];
  const float* wo  = (const float*)d_in[4];
  const float* qnw = (const float*)d_in[5];
  const float* knw = (const float*)d_in[6];
  float* out = (float*)d_out;

  char* ws = (char*)d_ws;
  unsigned short* Xb    = (unsigned short*)(ws);                 // [4096][2048]; dead after QKV GEMM
  unsigned short* Wqkvb = (unsigned short*)(ws + 16777216);      // [3072][2048] (wq|wk|wv)
  unsigned short* Wob   = (unsigned short*)(ws + 29360128);      // [2048][2048]
  unsigned short* QKb   = (unsigned short*)(ws + 37748736);      // [4096][2560]
  unsigned short* VTb   = (unsigned short*)(ws + 58720256);      // [512][4096]
  unsigned short* Obuf  = (unsigned short*)(ws + 62914560);      // [4096][2048]
  float* cosT = (float*)(ws + 79691776);                         // [2048][64]
  float* sinT = (float*)(ws + 80216064);

  // split-KV partial storage reuses the dead Xb region
  unsigned short* P2 = (unsigned short*)(ws);                    // [32768][128] bf16 = 8.39 MB
  float* m1G = (float*)(ws + 8388608);
  float* l1G = (float*)(ws + 8519680);
  float* m2G = (float*)(ws + 8650752);
  float* l2G = (float*)(ws + 8781824);

  fused_cast_kernel<<<dim3(512, 6), 256, 0, stream>>>(
      x, wq, wk, wv, wo,
      Xb, Wqkvb,
      Wqkvb + (size_t)D_DIM * D_DIM,
      Wqkvb + (size_t)NQK * D_DIM,
      Wob, cosT, sinT);

  // Merged QKV projection: Q,K -> QKb (stride 2560); V -> VTb transposed
  dim3 g1(NTOK / 128, NQKV / 128);            // 32 x 24 = 768 blocks
  gemm_bt_kernel<unsigned short, true><<<g1, 256, 0, stream>>>(
      Xb, Wqkvb, QKb, VTb, NTOK, NQKV, D_DIM);

  // RMSNorm+RoPE for Q and K rows (2 rows per wave; Q gets exp2-domain scale)
  norm_rope_kernel<<<(NTOK * (H_HEADS + KV_HEADS)) / 8, 256, 0, stream>>>(
      QKb, qnw, knw, cosT, sinT);

  attn_kernel<<<dim3(24, BATCH * H_HEADS), 256, 0, stream>>>(
      QKb, VTb, Obuf, P2, m1G, l1G, m2G, l2G);
  combine_kernel<<<2048, 256, 0, stream>>>(Obuf, P2, m1G, l1G, m2G, l2G);

  dim3 g2(NTOK / 128, D_DIM / 128);           // 32 x 16 = 512 blocks
  gemm_bt_kernel<float, false><<<g2, 256, 0, stream>>>(
      Obuf, Wob, out, nullptr, NTOK, D_DIM, D_DIM);
}

// Round 19
// 237.996 us; speedup vs baseline: 1.4236x; 1.4236x over previous
//
#include <hip/hip_runtime.h>
#include <hip/hip_bf16.h>
#include <stdint.h>
#include <stddef.h>

// Problem constants
#define D_DIM 2048
#define H_HEADS 16
#define KV_HEADS 4
#define HEAD_DIM 128
#define SEQ_L 2048
#define BATCH 2
#define NTOK 4096      // BATCH*SEQ_L
#define NQK 2560       // D + KV_HEADS*HEAD_DIM (Q+K rows; V handled via transposed path)
#define NQKV 3072      // Q+K+V rows in the merged projection

typedef __attribute__((ext_vector_type(4))) float f32x4;
typedef __attribute__((ext_vector_type(16))) float f32x16;
typedef __attribute__((ext_vector_type(8))) short bf16x8;

__device__ __forceinline__ unsigned short f2bf(float f) {
  __hip_bfloat16 h = __float2bfloat16(f);            // RTNE
  return *reinterpret_cast<unsigned short*>(&h);
}
__device__ __forceinline__ unsigned pack2(float lo, float hi) {
  return (unsigned)f2bf(lo) | ((unsigned)f2bf(hi) << 16);
}
__device__ __forceinline__ float bf2f(unsigned int s) {
  return __uint_as_float(s << 16);
}
__device__ __forceinline__ void plane32swap(unsigned& a, unsigned& b) {
  asm volatile("v_permlane32_swap_b32 %0, %1" : "+v"(a), "+v"(b));
}

__device__ __forceinline__ void async_copy16(const void* g, void* l) {
  __builtin_amdgcn_global_load_lds(
      (__attribute__((address_space(1))) void*)(g),
      (__attribute__((address_space(3))) void*)(l),
      16, 0, 0);
}

// ---------------- fused fp32->bf16 casts + RoPE table (segment per blockIdx.y) ----------------
__device__ __forceinline__ void cast_seg(const float* __restrict__ src,
                                         unsigned short* __restrict__ dst,
                                         int n4, int gid, int stride) {
  for (int i = gid; i < n4; i += stride) {
    float4 v = *reinterpret_cast<const float4*>(src + (size_t)i * 4);
    uint2 o;
    o.x = pack2(v.x, v.y);
    o.y = pack2(v.z, v.w);
    *reinterpret_cast<uint2*>(dst + (size_t)i * 4) = o;
  }
}

__global__ __launch_bounds__(256) void fused_cast_kernel(
    const float* __restrict__ s0, const float* __restrict__ s1,
    const float* __restrict__ s2, const float* __restrict__ s3,
    const float* __restrict__ s4,
    unsigned short* __restrict__ d0, unsigned short* __restrict__ d1,
    unsigned short* __restrict__ d2, unsigned short* __restrict__ d3,
    unsigned short* __restrict__ d4,
    float* __restrict__ cosT, float* __restrict__ sinT) {
  int gid = blockIdx.x * blockDim.x + threadIdx.x;
  const int stride = 512 * 256;
  const size_t xh = (size_t)NTOK * D_DIM / 2;       // half of x, elements
  switch (blockIdx.y) {
    case 0: cast_seg(s0, d0, (NTOK * D_DIM) / 8, gid, stride); break;      // x lo half
    case 1: cast_seg(s0 + xh, d0 + xh, (NTOK * D_DIM) / 8, gid, stride); break;  // x hi half
    case 2: cast_seg(s1, d1, (D_DIM * D_DIM) / 4, gid, stride); break;     // wq
    case 3: cast_seg(s4, d4, (D_DIM * D_DIM) / 4, gid, stride); break;     // wo
    case 4:
      cast_seg(s2, d2, (512 * D_DIM) / 4, gid, stride);                    // wk
      cast_seg(s3, d3, (512 * D_DIM) / 4, gid, stride);                    // wv
      break;
    default: {                                                             // RoPE table
      int p = gid & 63;
      float l = (float)(gid >> 6);
      float inv = powf(10000.0f, -(float)p / 64.0f);
      float ang = l * inv;
      cosT[gid] = cosf(ang);
      sinT[gid] = sinf(ang);
    }
  }
}

// ---------------- GEMM: C[M,N] = A[M,K] * B[N,K]^T  (bf16 in, OutT out) ----------------
__device__ __forceinline__ void store_out(unsigned short* p, float v) { *p = f2bf(v); }
__device__ __forceinline__ void store_out(float* p, float v) { *p = v; }

template <typename OutT, bool VSPLIT>
__global__ __launch_bounds__(256) void gemm_bt_kernel(const unsigned short* __restrict__ A,
                                                      const unsigned short* __restrict__ B,
                                                      OutT* __restrict__ C,
                                                      unsigned short* __restrict__ vt,
                                                      int M, int N, int K) {
  __shared__ unsigned short Alds[128 * 32];
  __shared__ unsigned short Blds[128 * 32];
  const int tid = threadIdx.x;
  const int wave = tid >> 6;
  const int lane = tid & 63;
  const int l15 = lane & 15;
  const int l4 = lane >> 4;

  // XCD-aware bijective swizzle (T1)
  const int nwg = gridDim.x * gridDim.y;
  const int orig = blockIdx.y * gridDim.x + blockIdx.x;
  const int cpx = nwg >> 3;
  const int swz = (orig & 7) * cpx + (orig >> 3);
  const int m0 = (swz % gridDim.x) * 128;
  const int n0 = (swz / gridDim.x) * 128;

  const int wm = (wave >> 1) * 64;
  const int wn = (wave & 1) * 64;

  f32x4 acc[4][4] = {};

  const int soff0 = wave * 1024 + lane * 16;  // bytes within 8KB tile

  for (int kt = 0; kt < K; kt += 32) {
#pragma unroll
    for (int inst = 0; inst < 2; ++inst) {
      int off = soff0 + inst * 4096;
      int row = off >> 6;    // 64 bytes (32 bf16) per LDS row
      int colb = off & 63;
      const char* ga = (const char*)(A + (size_t)(m0 + row) * K + kt) + colb;
      async_copy16(ga, (char*)Alds + off);
      const char* gb = (const char*)(B + (size_t)(n0 + row) * K + kt) + colb;
      async_copy16(gb, (char*)Blds + off);
    }
    __syncthreads();
    bf16x8 af[4], bfr[4];
#pragma unroll
    for (int i = 0; i < 4; ++i)
      af[i] = *reinterpret_cast<const bf16x8*>(Alds + (wm + i * 16 + l15) * 32 + l4 * 8);
#pragma unroll
    for (int j = 0; j < 4; ++j)
      bfr[j] = *reinterpret_cast<const bf16x8*>(Blds + (wn + j * 16 + l15) * 32 + l4 * 8);
#pragma unroll
    for (int i = 0; i < 4; ++i)
#pragma unroll
      for (int j = 0; j < 4; ++j)
        acc[i][j] = __builtin_amdgcn_mfma_f32_16x16x32_bf16(af[i], bfr[j], acc[i][j], 0, 0, 0);
    __syncthreads();
  }

  if (VSPLIT && n0 >= NQK) {
    // V block: write transposed into vt[dv][token]
#pragma unroll
    for (int i = 0; i < 4; ++i)
#pragma unroll
      for (int j = 0; j < 4; ++j) {
        int vrow = n0 + wn + j * 16 + l15 - NQK;
        int tok0 = m0 + wm + i * 16 + l4 * 4;
        ushort4 pk;
        pk.x = f2bf(acc[i][j][0]);
        pk.y = f2bf(acc[i][j][1]);
        pk.z = f2bf(acc[i][j][2]);
        pk.w = f2bf(acc[i][j][3]);
        *reinterpret_cast<ushort4*>(vt + (size_t)vrow * NTOK + tok0) = pk;
      }
    return;
  }

  const int cstride = VSPLIT ? NQK : N;
#pragma unroll
  for (int i = 0; i < 4; ++i)
#pragma unroll
    for (int j = 0; j < 4; ++j) {
      int col = n0 + wn + j * 16 + l15;
#pragma unroll
      for (int r = 0; r < 4; ++r) {
        int row = m0 + wm + i * 16 + l4 * 4 + r;
        store_out(C + (size_t)row * cstride + col, acc[i][j][r]);
      }
    }
}

// ---------------- RMSNorm + RoPE (in-place, 2 rows per wave, 8B/lane) ----------------
__global__ __launch_bounds__(256) void norm_rope_kernel(unsigned short* __restrict__ qk,
                                                        const float* __restrict__ qw,
                                                        const float* __restrict__ kw,
                                                        const float* __restrict__ cosT,
                                                        const float* __restrict__ sinT) {
  int gw = (blockIdx.x * blockDim.x + threadIdx.x) >> 6;  // wave id
  int lane = threadIdx.x & 63;
  int half = lane >> 5;         // which of the wave's 2 rows
  int L = lane & 31;            // dim-quad index: dims 4L..4L+3
  int rho = gw * 2 + half;      // row id
  unsigned short* rowp;
  const float* w;
  int m;
  float sc;
  if (rho < NTOK * H_HEADS) {
    m = rho >> 4;
    rowp = qk + (size_t)m * NQK + (rho & 15) * HEAD_DIM;
    w = qw;
    sc = 0.08838834764831845f;   // fold 1/sqrt(128) into Q
  } else {
    int r2 = rho - NTOK * H_HEADS;
    m = r2 >> 2;
    rowp = qk + (size_t)m * NQK + D_DIM + (r2 & 3) * HEAD_DIM;
    w = kw;
    sc = 1.0f;
  }
  int l = m & (SEQ_L - 1);
  uint2 pr = *reinterpret_cast<const uint2*>(rowp + L * 4);
  float e0 = bf2f(pr.x & 0xffffu), o0 = bf2f(pr.x >> 16);
  float e1 = bf2f(pr.y & 0xffffu), o1 = bf2f(pr.y >> 16);
  float ss = e0 * e0 + o0 * o0 + e1 * e1 + o1 * o1;
#pragma unroll
  for (int off = 1; off < 32; off <<= 1) ss += __shfl_xor(ss, off);  // per 32-lane half
  float rsn = rsqrtf(ss * (1.0f / 128.0f) + 1e-6f) * sc;
  float4 wv4 = *reinterpret_cast<const float4*>(w + L * 4);
  float2 c2 = *reinterpret_cast<const float2*>(cosT + l * 64 + L * 2);
  float2 s2 = *reinterpret_cast<const float2*>(sinT + l * 64 + L * 2);
  float xe0 = e0 * rsn * wv4.x, xo0 = o0 * rsn * wv4.y;
  float xe1 = e1 * rsn * wv4.z, xo1 = o1 * rsn * wv4.w;
  uint2 outp;
  outp.x = pack2(xe0 * c2.x - xo0 * s2.x, xe0 * s2.x + xo0 * c2.x);
  outp.y = pack2(xe1 * c2.y - xo1 * s2.y, xe1 * s2.y + xo1 * c2.y);
  *reinterpret_cast<uint2*>(rowp + L * 4) = outp;
}

// ---------------- Flash attention v9 (R15/R17-exact champion) ----------------
// K single-buffered, V double-buffered, all staging via global_load_lds.
// LDS 48.5KB -> 3 blocks/CU, 12 waves/CU. launch_bounds(256,3): VGPR 84, no spill.
__global__ __launch_bounds__(256, 3) void attn_kernel(const unsigned short* __restrict__ qk,
                                                      const unsigned short* __restrict__ vt,
                                                      unsigned short* __restrict__ obuf,
                                                      unsigned short* __restrict__ p2,
                                                      float* __restrict__ m1G, float* __restrict__ l1G,
                                                      float* __restrict__ m2G, float* __restrict__ l2G) {
  __shared__ unsigned short Kl[64 * 128];      // [key][d], XOR-swizzled rows (256B), single
  __shared__ unsigned short Vl[2][128 * 64];   // [d][key], XOR-swizzled rows (128B), dbuf
  __shared__ float invl[128];

  const int tid = threadIdx.x;
  const int w = tid >> 6, lane = tid & 63;
  const int l31 = lane & 31, hi = lane >> 5;

  const int jx = blockIdx.x;                   // 0..23, roughly longest-first
  int qt, seg, kv_begin, kv_end;
  bool split;
  if (jx < 16) {
    split = true;
    qt = 15 - (jx >> 1);
    seg = jx & 1;
    int nt = qt + 1;
    kv_begin = seg * nt;
    kv_end = kv_begin + nt;
  } else {
    split = false;
    seg = 0;
    qt = 23 - jx;
    kv_begin = 0;
    kv_end = 2 * qt + 2;
  }
  const int q0 = qt * 128;

  const int bh = blockIdx.y;
  const int b = bh >> 4, h = bh & 15, kvh = h >> 2;

  const unsigned short* Qg = qk + (size_t)(b * SEQ_L + q0 + w * 32 + l31) * NQK + h * HEAD_DIM;
  const unsigned short* Kg = qk + (size_t)(b * SEQ_L) * NQK + D_DIM + kvh * HEAD_DIM;
  const unsigned short* Vg = vt + (size_t)(kvh * HEAD_DIM) * NTOK + b * SEQ_L;

  // Q fragments in registers: qf[kk] = Q[q=l31][kk*16 + hi*8 .. +7]
  bf16x8 qf[8];
#pragma unroll
  for (int kk = 0; kk < 8; ++kk)
    qf[kk] = *reinterpret_cast<const bf16x8*>(Qg + kk * 16 + hi * 8);

  f32x16 accO[4] = {};
  float m_run = -1e30f, l_run = 0.0f;

  const int qmin_w = q0 + w * 32;
  const int qmax_w = qmin_w + 31;
  const int qg = qmin_w + l31;

  auto stageK = [&](int kt) {
#pragma unroll
    for (int i = 0; i < 4; ++i) {
      int o = (i * 256 + tid) * 16;   // byte offset within 16KB K tile
      int row = o >> 8;
      int scb = (o & 255) ^ ((row & 7) << 4);
      const char* src = (const char*)(Kg + (size_t)(kt * 64 + row) * NQK) + scb;
      async_copy16(src, (char*)Kl + o);
    }
  };
  auto stageV = [&](int vb, int kt) {
#pragma unroll
    for (int i = 0; i < 4; ++i) {
      int o = (i * 256 + tid) * 16;   // byte offset within 16KB V^T tile
      int d = o >> 7;
      int skb = (o & 127) ^ ((d & 7) << 4);
      const char* src = (const char*)(Vg + (size_t)d * NTOK + kt * 64) + skb;
      async_copy16(src, (char*)(&Vl[vb][0]) + o);
    }
  };

  stageK(kv_begin);
  stageV(0, kv_begin);
  asm volatile("s_waitcnt vmcnt(0)" ::: "memory");
  __syncthreads();

  int vb = 0;
  for (int kt = kv_begin; kt < kv_end; ++kt) {
    const bool active = (kt * 64 <= qmax_w);
    bf16x8 pa[2][2];

    if (active) {
      // ---- QK^T: S^T[key][q], two 32-key sub-tiles ----
      f32x16 st[2] = {};
      __builtin_amdgcn_s_setprio(1);
#pragma unroll
      for (int stile = 0; stile < 2; ++stile) {
#pragma unroll
        for (int kk = 0; kk < 8; ++kk) {
          int row = stile * 32 + l31;
          int off = (row << 8) + (((kk << 5) + (hi << 4)) ^ ((l31 & 7) << 4));
          bf16x8 kf = *reinterpret_cast<const bf16x8*>((const char*)Kl + off);
          st[stile] = __builtin_amdgcn_mfma_f32_32x32x16_bf16(kf, qf[kk], st[stile], 0, 0, 0);
        }
      }
      __builtin_amdgcn_s_setprio(0);

      // ---- mask + per-lane online softmax (scale pre-folded into Q) ----
      const bool need_mask = (kt * 64 + 63 > qmin_w);
      float tmax = -1e30f;
#pragma unroll
      for (int stile = 0; stile < 2; ++stile)
#pragma unroll
        for (int r = 0; r < 16; ++r) {
          float s = st[stile][r];
          if (need_mask) {
            int key = kt * 64 + stile * 32 + (r & 3) + ((r >> 2) << 3) + (hi << 2);
            if (key > qg) s = -1e30f;
          }
          st[stile][r] = s;
          tmax = fmaxf(tmax, s);
        }
      tmax = fmaxf(tmax, __shfl_xor(tmax, 32));

      // ---- defer-max (T13) ----
      if (!__all(tmax - m_run <= 8.0f)) {
        float mnew = fmaxf(m_run, tmax);
        float corr = __expf(m_run - mnew);
        m_run = mnew;
        l_run *= corr;
        float corrq[16];
#pragma unroll
        for (int r = 0; r < 16; ++r) {
          int qi = (r & 3) + ((r >> 2) << 3) + (hi << 2);
          corrq[r] = __shfl(corr, qi);
        }
#pragma unroll
        for (int dt = 0; dt < 4; ++dt)
#pragma unroll
          for (int r = 0; r < 16; ++r) accO[dt][r] *= corrq[r];
      }

      float rsum = 0.0f;
#pragma unroll
      for (int stile = 0; stile < 2; ++stile)
#pragma unroll
        for (int r = 0; r < 16; ++r) {
          float pe = __expf(st[stile][r] - m_run);
          st[stile][r] = pe;
          rsum += pe;
        }
      rsum += __shfl_xor(rsum, 32);
      l_run += rsum;

      // ---- P -> bf16 A-fragments via permlane32_swap (T12) ----
#pragma unroll
      for (int stile = 0; stile < 2; ++stile)
#pragma unroll
        for (int kc = 0; kc < 2; ++kc) {
          int rb = kc * 8;
          unsigned a  = pack2(st[stile][rb + 0], st[stile][rb + 1]);
          unsigned bw = pack2(st[stile][rb + 4], st[stile][rb + 5]);
          unsigned c  = pack2(st[stile][rb + 2], st[stile][rb + 3]);
          unsigned d  = pack2(st[stile][rb + 6], st[stile][rb + 7]);
          plane32swap(a, bw);
          plane32swap(c, d);
          union { bf16x8 v; unsigned u[4]; } uu;
          uu.u[0] = a; uu.u[1] = c; uu.u[2] = bw; uu.u[3] = d;
          pa[stile][kc] = uu.v;
        }
    }

    // V(kt+1) -> other V buffer (no reader conflict; completion enforced at loop end)
    if (kt + 1 < kv_end) stageV(vb ^ 1, kt + 1);

    __syncthreads();                // all waves done reading Kl(kt)

    if (kt + 1 < kv_end) stageK(kt + 1);   // overwrite Kl; latency hides under PV

    if (active) {
      // ---- PV: O[q][d] += P * V ----
      __builtin_amdgcn_s_setprio(1);
#pragma unroll
      for (int dt = 0; dt < 4; ++dt) {
        int drow = dt * 32 + l31;
#pragma unroll
        for (int stile = 0; stile < 2; ++stile)
#pragma unroll
          for (int kc = 0; kc < 2; ++kc) {
            int off = (drow << 7) + (((stile << 6) + (kc << 5) + (hi << 4)) ^ ((l31 & 7) << 4));
            bf16x8 vf = *reinterpret_cast<const bf16x8*>((const char*)(&Vl[vb][0]) + off);
            accO[dt] = __builtin_amdgcn_mfma_f32_32x32x16_bf16(pa[stile][kc], vf, accO[dt], 0, 0, 0);
          }
      }
      __builtin_amdgcn_s_setprio(0);
    }

    asm volatile("s_waitcnt vmcnt(0)" ::: "memory");
    __syncthreads();                // K(kt+1), V(kt+1) resident
    vb ^= 1;
  }

  if (!split) {
    // ---- direct epilogue: O /= l ----
    if (hi == 0) invl[w * 32 + l31] = 1.0f / l_run;
    __syncthreads();
#pragma unroll
    for (int dt = 0; dt < 4; ++dt)
#pragma unroll
      for (int r = 0; r < 16; ++r) {
        int qrow = (r & 3) + ((r >> 2) << 3) + (hi << 2);
        float val = accO[dt][r] * invl[w * 32 + qrow];
        int tok = b * SEQ_L + q0 + w * 32 + qrow;
        obuf[(size_t)tok * D_DIM + h * HEAD_DIM + dt * 32 + l31] = f2bf(val);
      }
  } else {
    // ---- partial epilogue: unnormalized O + (m,l) per row ----
    const int rowbase = bh * 1024 + (qt - 8) * 128;  // split rows: qt in [8,16)
    if (hi == 0) {
      int rr = rowbase + w * 32 + l31;
      if (seg == 0) { m1G[rr] = m_run; l1G[rr] = l_run; }
      else          { m2G[rr] = m_run; l2G[rr] = l_run; }
    }
#pragma unroll
    for (int dt = 0; dt < 4; ++dt)
#pragma unroll
      for (int r = 0; r < 16; ++r) {
        int qrow = (r & 3) + ((r >> 2) << 3) + (hi << 2);
        float val = accO[dt][r];
        if (seg == 0) {
          int tok = b * SEQ_L + q0 + w * 32 + qrow;
          obuf[(size_t)tok * D_DIM + h * HEAD_DIM + dt * 32 + l31] = f2bf(val);
        } else {
          size_t prow = (size_t)(rowbase + w * 32 + qrow);
          p2[prow * HEAD_DIM + dt * 32 + l31] = f2bf(val);
        }
      }
  }
}

// ---------------- combine kernel: merge split-KV partials into obuf ----------------
__global__ __launch_bounds__(256) void combine_kernel(unsigned short* __restrict__ obuf,
                                                      const unsigned short* __restrict__ p2,
                                                      const float* __restrict__ m1G, const float* __restrict__ l1G,
                                                      const float* __restrict__ m2G, const float* __restrict__ l2G) {
  int gid = blockIdx.x * blockDim.x + threadIdx.x;   // 32768 rows x 16 chunks
  int row = gid >> 4;
  int dc = (gid & 15) * 8;
  int bh = row >> 10;
  int rem = row & 1023;
  int qt = 8 + (rem >> 7);
  int rr = rem & 127;
  int b = bh >> 4, h = bh & 15;
  size_t tok = (size_t)(b * SEQ_L + qt * 128 + rr);

  float m1 = m1G[row], l1 = l1G[row], m2 = m2G[row], l2 = l2G[row];
  float mm = fmaxf(m1, m2);
  float w1 = __expf(m1 - mm), w2 = __expf(m2 - mm);
  float inv = 1.0f / (w1 * l1 + w2 * l2);

  unsigned short* op = obuf + tok * D_DIM + h * HEAD_DIM + dc;
  const unsigned short* pp = p2 + (size_t)row * HEAD_DIM + dc;
  ushort4 a0 = *reinterpret_cast<const ushort4*>(op);
  ushort4 a1 = *reinterpret_cast<const ushort4*>(op + 4);
  ushort4 b0 = *reinterpret_cast<const ushort4*>(pp);
  ushort4 b1 = *reinterpret_cast<const ushort4*>(pp + 4);
  ushort4 o0, o1;
  o0.x = f2bf((w1 * bf2f(a0.x) + w2 * bf2f(b0.x)) * inv);
  o0.y = f2bf((w1 * bf2f(a0.y) + w2 * bf2f(b0.y)) * inv);
  o0.z = f2bf((w1 * bf2f(a0.z) + w2 * bf2f(b0.z)) * inv);
  o0.w = f2bf((w1 * bf2f(a0.w) + w2 * bf2f(b0.w)) * inv);
  o1.x = f2bf((w1 * bf2f(a1.x) + w2 * bf2f(b1.x)) * inv);
  o1.y = f2bf((w1 * bf2f(a1.y) + w2 * bf2f(b1.y)) * inv);
  o1.z = f2bf((w1 * bf2f(a1.z) + w2 * bf2f(b1.z)) * inv);
  o1.w = f2bf((w1 * bf2f(a1.w) + w2 * bf2f(b1.w)) * inv);
  *reinterpret_cast<ushort4*>(op) = o0;
  *reinterpret_cast<ushort4*>(op + 4) = o1;
}

// ---------------- launcher ----------------
extern "C" void kernel_launch(void* const* d_in, const int* in_sizes, int n_in,
                              void* d_out, int out_size, void* d_ws, size_t ws_size,
                              hipStream_t stream) {
  const float* x   = (const float*)d_in[0];
  const float* wq  = (const float*)d_in[1];
  const float* wk  = (const float*)d_in[2];
  const float* wv  = (const float*)d_in[3];
  const float* wo  = (const float*)d_in[4];
  const float* qnw = (const float*)d_in[5];
  const float* knw = (const float*)d_in[6];
  float* out = (float*)d_out;

  char* ws = (char*)d_ws;
  unsigned short* Xb    = (unsigned short*)(ws);                 // [4096][2048]; dead after QKV GEMM
  unsigned short* Wqkvb = (unsigned short*)(ws + 16777216);      // [3072][2048] (wq|wk|wv)
  unsigned short* Wob   = (unsigned short*)(ws + 29360128);      // [2048][2048]
  unsigned short* QKb   = (unsigned short*)(ws + 37748736);      // [4096][2560]
  unsigned short* VTb   = (unsigned short*)(ws + 58720256);      // [512][4096]
  unsigned short* Obuf  = (unsigned short*)(ws + 62914560);      // [4096][2048]
  float* cosT = (float*)(ws + 79691776);                         // [2048][64]
  float* sinT = (float*)(ws + 80216064);

  // split-KV partial storage reuses the dead Xb region
  unsigned short* P2 = (unsigned short*)(ws);                    // [32768][128] bf16 = 8.39 MB
  float* m1G = (float*)(ws + 8388608);
  float* l1G = (float*)(ws + 8519680);
  float* m2G = (float*)(ws + 8650752);
  float* l2G = (float*)(ws + 8781824);

  fused_cast_kernel<<<dim3(512, 6), 256, 0, stream>>>(
      x, wq, wk, wv, wo,
      Xb, Wqkvb,
      Wqkvb + (size_t)D_DIM * D_DIM,
      Wqkvb + (size_t)NQK * D_DIM,
      Wob, cosT, sinT);

  // Merged QKV projection: Q,K -> QKb (stride 2560); V -> VTb transposed
  dim3 g1(NTOK / 128, NQKV / 128);            // 32 x 24 = 768 blocks
  gemm_bt_kernel<unsigned short, true><<<g1, 256, 0, stream>>>(
      Xb, Wqkvb, QKb, VTb, NTOK, NQKV, D_DIM);

  // RMSNorm+RoPE for Q and K rows (2 rows per wave)
  norm_rope_kernel<<<(NTOK * (H_HEADS + KV_HEADS)) / 8, 256, 0, stream>>>(
      QKb, qnw, knw, cosT, sinT);

  attn_kernel<<<dim3(24, BATCH * H_HEADS), 256, 0, stream>>>(
      QKb, VTb, Obuf, P2, m1G, l1G, m2G, l2G);
  combine_kernel<<<2048, 256, 0, stream>>>(Obuf, P2, m1G, l1G, m2G, l2G);

  dim3 g2(NTOK / 128, D_DIM / 128);           // 32 x 16 = 512 blocks
  gemm_bt_kernel<float, false><<<g2, 256, 0, stream>>>(
      Obuf, Wob, out, nullptr, NTOK, D_DIM, D_DIM);
}